// Round 2
// baseline (15263.933 us; speedup 1.0000x reference)
//
#include <hip/hip_runtime.h>
#include <stdint.h>

// Problem constants (Embedder_66932770341523)
#define TSEQ 2048
#define NB   64
#define HD   128
#define G3   384

typedef __bf16 bf16_t;
typedef __bf16 bf16x8 __attribute__((ext_vector_type(8)));
typedef float  f32x4  __attribute__((ext_vector_type(4)));

union B8 { uint4 u; bf16x8 v; };
static_assert(sizeof(B8) == 16, "B8 must be 16B");

__device__ __forceinline__ float fast_sigmoid(float x) {
    float e = __builtin_amdgcn_exp2f(-1.44269504f * x);
    return __builtin_amdgcn_rcpf(1.0f + e);
}
__device__ __forceinline__ float fast_tanh(float x) {
    x = fminf(9.0f, fmaxf(-9.0f, x));
    float e = __builtin_amdgcn_exp2f(2.88539008f * x);   // exp(2x)
    return 1.0f - 2.0f * __builtin_amdgcn_rcpf(1.0f + e);
}

#define MFMA16(A_, B_, C_) (C_) = __builtin_amdgcn_mfma_f32_16x16x32_bf16((A_), (B_), (C_), 0, 0, 0)

// MFMA 16x16x32 bf16 fragment maps (HW-verified per guide m89/m91/m120):
//   A: lane l, elem j -> A[l&15][(l>>4)*8 + j]
//   B: lane l, elem j -> B[(l>>4)*8 + j][l&15]
//   C/D: lane l, reg i -> C[(l>>4)*4 + i][l&15]

// One GRU timestep. PV = t&1 (literal 0/1 so xf[]/ldsh[] indices fold to constants).
#define GRU_STEP(TT, PV)                                                              \
  {                                                                                   \
    B8 ah[2][4];                                                                      \
    _Pragma("unroll") for (int hl = 0; hl < 2; ++hl) {                                \
      _Pragma("unroll") for (int q = 0; q < 4; ++q) {                                 \
        ah[hl][q].u = ldsh[(PV) ^ 1][hl][q][lane];                                    \
      }                                                                               \
    }                                                                                 \
    if ((TT) + 1 < TSEQ) { /* prefetch x(t+1); hides global latency under step */     \
      LOADX((PV) ^ 1, (TT) + 1);                                                      \
    }                                                                                 \
    f32x4 accZ  = {bZ, bZ, bZ, bZ};                                                   \
    f32x4 accR  = {bR, bR, bR, bR};                                                   \
    f32x4 accXC = {bXC, bXC, bXC, bXC};                                               \
    f32x4 accHC = {bHC, bHC, bHC, bHC};                                               \
    _Pragma("unroll") for (int q = 0; q < 4; ++q) {                                   \
      MFMA16(ah[0][q].v, Br[0][q], accZ);   /* gh, hi */                              \
      MFMA16(ah[0][q].v, Br[1][q], accR);                                             \
      MFMA16(ah[0][q].v, Br[2][q], accHC);                                            \
      MFMA16(ah[1][q].v, Br[0][q], accZ);   /* gh, lo */                              \
      MFMA16(ah[1][q].v, Br[1][q], accR);                                             \
      MFMA16(ah[1][q].v, Br[2][q], accHC);                                            \
      MFMA16(xf[(PV)][0][q].v, Bi_[0][q], accZ);  /* gx, hi */                        \
      MFMA16(xf[(PV)][0][q].v, Bi_[1][q], accR);                                      \
      MFMA16(xf[(PV)][0][q].v, Bi_[2][q], accXC);                                     \
      MFMA16(xf[(PV)][1][q].v, Bi_[0][q], accZ);  /* gx, lo */                        \
      MFMA16(xf[(PV)][1][q].v, Bi_[1][q], accR);                                      \
      MFMA16(xf[(PV)][1][q].v, Bi_[2][q], accXC);                                     \
    }                                                                                 \
    _Pragma("unroll") for (int i = 0; i < 4; ++i) {                                   \
      const float zg = fast_sigmoid(accZ[i]);                                         \
      const float rg = fast_sigmoid(accR[i]);                                         \
      const float cd = fast_tanh(accXC[i] + rg * accHC[i]); /* reset_after: r*(hh+br)*/\
      const float hn = cd + zg * (hprev[i] - cd);           /* z*h + (1-z)*cand */    \
      hprev[i] = hn;                                                                  \
      const bf16_t hhi = (bf16_t)hn;                                                  \
      const bf16_t hlo = (bf16_t)(hn - (float)hhi);                                   \
      const int mrow = 4 * quad + i;                                                  \
      ((bf16_t*)&ldsh[(PV)][0][qq][lamb + mrow])[jj] = hhi;                           \
      ((bf16_t*)&ldsh[(PV)][1][qq][lamb + mrow])[jj] = hlo;                           \
      const int orow = (TT) * NB + 16 * bx + mrow;                                    \
      o_hi[orow * HD + cc] = hhi;                                                     \
      o_lo[orow * HD + cc] = hlo;                                                     \
    }                                                                                 \
    __syncthreads();                                                                  \
  }

// Fused GRU layer scan: grid = 4 WGs (16 batch rows each), 512 threads = 8 waves,
// wave w owns h-columns [16w,16w+16) => gate columns {16w.., 128+16w.., 256+16w..}.
// h state: fp32 in registers (C-layout); matmul A-operand: bf16 hi+lo via LDS.
// XMODE: 1 = x is bf16 hi+lo pair ([T,B,D]); 2 = x is fp32 (split to hi+lo in-kernel).
template <bool BTD, int XMODE>
__global__ __launch_bounds__(512, 2) void gru_scan(
    const float* __restrict__ xf32,
    const bf16_t* __restrict__ x_hi, const bf16_t* __restrict__ x_lo,
    const float* __restrict__ Wrec, const float* __restrict__ Win,
    const float* __restrict__ bin, const float* __restrict__ brec,
    bf16_t* __restrict__ o_hi, bf16_t* __restrict__ o_lo)
{
    const int tid  = threadIdx.x;
    const int w    = tid >> 6;
    const int lane = tid & 63;
    const int l15  = lane & 15;
    const int quad = lane >> 4;
    const int bx   = blockIdx.x;

    // [parity][hi/lo][kfrag q][lane] -- h stored in exact A-fragment order:
    // frag reads are contiguous-16B-per-lane => canonical conflict-free pattern.
    __shared__ uint4 ldsh[2][2][4][64];

    // B-fragments resident in registers for the whole scan (fp32 weights -> bf16 once).
    bf16x8 Br[3][4];
    bf16x8 Bi_[3][4];
#pragma unroll
    for (int g = 0; g < 3; ++g) {
#pragma unroll
        for (int q = 0; q < 4; ++q) {
            const int col = 128 * g + 16 * w + l15;
#pragma unroll
            for (int j = 0; j < 8; ++j) {
                const int row = 32 * q + 8 * quad + j;
                Br[g][q][j]  = (bf16_t)Wrec[row * G3 + col];
                Bi_[g][q][j] = (bf16_t)Win[row * G3 + col];
            }
        }
    }

    const int cc    = 16 * w + l15;          // this lane's h-column
    const float bZ  = bin[cc] + brec[cc];
    const float bR  = bin[128 + cc] + brec[128 + cc];
    const float bXC = bin[256 + cc];         // candidate: input bias (outside r*)
    const float bHC = brec[256 + cc];        // candidate: recurrent bias (inside r*)

    const int brow  = 16 * bx + l15;         // batch row for A-operand m = l15
    const int xbase = BTD ? brow * (TSEQ * HD) : brow * HD;  // X is [B,T,D]; H is [T,B,D]
    const int xstr  = BTD ? HD : NB * HD;

    {   // zero parity-1 h buffers (read at t=0): 512 threads x one uint4
        uint4 z4; z4.x = z4.y = z4.z = z4.w = 0u;
        ldsh[1][tid >> 8][(tid >> 6) & 3][tid & 63] = z4;
    }

    // constant LDS write mapping for this lane: A[m][k=cc] lives in frag q=cc>>5,
    // lane = m + 16*((cc>>3)&3), elem j = cc&7
    const int qq   = cc >> 5;
    const int lamb = 16 * ((cc >> 3) & 3);
    const int jj   = cc & 7;

    float hprev[4] = {0.f, 0.f, 0.f, 0.f};

    B8 xf[2][2][4];                           // double-buffered x fragments (hi+lo)

    auto LOADX = [&](int dst, int tt) {
        if constexpr (XMODE == 2) {
#pragma unroll
            for (int q = 0; q < 4; ++q) {
                const float* p = xf32 + (xbase + tt * xstr + 32 * q + 8 * quad);
                const float4 f0 = *(const float4*)p;
                const float4 f1 = *(const float4*)(p + 4);
                const float f[8] = {f0.x, f0.y, f0.z, f0.w, f1.x, f1.y, f1.z, f1.w};
#pragma unroll
                for (int j = 0; j < 8; ++j) {
                    const bf16_t hh = (bf16_t)f[j];
                    xf[dst][0][q].v[j] = hh;
                    xf[dst][1][q].v[j] = (bf16_t)(f[j] - (float)hh);
                }
            }
        } else {
#pragma unroll
            for (int q = 0; q < 4; ++q) {
                xf[dst][0][q].u = *(const uint4*)(x_hi + (xbase + tt * xstr + 32 * q + 8 * quad));
                xf[dst][1][q].u = *(const uint4*)(x_lo + (xbase + tt * xstr + 32 * q + 8 * quad));
            }
        }
    };

    LOADX(0, 0);

    __syncthreads();

    for (int t = 0; t < TSEQ; t += 2) {
        GRU_STEP(t, 0)
        GRU_STEP(t + 1, 1)
    }
}

// out = sigmoid(H3 @ W_out + b_out), H3 = hi+lo bf16 [T*64][128], out fp32 [B][T][128]
__global__ __launch_bounds__(512, 2) void out_proj(
    const bf16_t* __restrict__ h_hi, const bf16_t* __restrict__ h_lo,
    const float* __restrict__ Wout, const float* __restrict__ bout,
    float* __restrict__ out)
{
    const int tid  = threadIdx.x;
    const int w    = tid >> 6;     // wave = N-tile (8 tiles of 16 cols = 128)
    const int lane = tid & 63;
    const int l15  = lane & 15;
    const int quad = lane >> 4;

    bf16x8 Bw[4];
#pragma unroll
    for (int q = 0; q < 4; ++q)
#pragma unroll
        for (int j = 0; j < 8; ++j)
            Bw[q][j] = (bf16_t)Wout[(32 * q + 8 * quad + j) * HD + 16 * w + l15];

    const float bb = bout[16 * w + l15];

    const int NT = (TSEQ * NB) / 16;   // 8192 M-tiles
    for (int tile = blockIdx.x; tile < NT; tile += gridDim.x) {
        B8 ah[2][4];
        const int rowb = tile * 16 + l15;
#pragma unroll
        for (int q = 0; q < 4; ++q) {
            ah[0][q].u = *(const uint4*)(h_hi + (rowb * HD + 32 * q + 8 * quad));
            ah[1][q].u = *(const uint4*)(h_lo + (rowb * HD + 32 * q + 8 * quad));
        }
        f32x4 acc = {bb, bb, bb, bb};
#pragma unroll
        for (int q = 0; q < 4; ++q) {
            MFMA16(ah[0][q].v, Bw[q], acc);
            MFMA16(ah[1][q].v, Bw[q], acc);
        }
        const int t  = tile >> 2;           // 4 M-tiles per timestep (64 batch rows)
        const int b0 = (tile & 3) * 16;
#pragma unroll
        for (int i = 0; i < 4; ++i) {
            const float s = fast_sigmoid(acc[i]);
            const int b = b0 + 4 * quad + i;
            out[(b * TSEQ + t) * HD + 16 * w + l15] = s;
        }
    }
}

extern "C" void kernel_launch(void* const* d_in, const int* in_sizes, int n_in,
                              void* d_out, int out_size, void* d_ws, size_t ws_size,
                              hipStream_t stream) {
    const float* X   = (const float*)d_in[0];  // [64][2048][128] fp32
    const float* Wk  = (const float*)d_in[1];  // kernel [128][384] fp32
    const float* Wr  = (const float*)d_in[2];  // rec_kernel [128][384] fp32
    const float* bi  = (const float*)d_in[3];  // bias_in [384] fp32
    const float* br  = (const float*)d_in[4];  // bias_rec [384] fp32
    const float* Wo  = (const float*)d_in[5];  // W_out [128][128] fp32
    const float* bo  = (const float*)d_in[6];  // b_out [128] fp32
    float* out = (float*)d_out;                // [64][2048][128] fp32

    const size_t seg = (size_t)TSEQ * NB * HD * sizeof(bf16_t); // 32 MiB
    if (ws_size < 4 * seg) return;  // distinctive fail (zero out) instead of OOB scribble
    char* ws = (char*)d_ws;
    bf16_t* Ahi = (bf16_t*)(ws);
    bf16_t* Alo = (bf16_t*)(ws + seg);
    bf16_t* Bhi = (bf16_t*)(ws + 2 * seg);
    bf16_t* Blo = (bf16_t*)(ws + 3 * seg);

    // layer 1: x = X ([B,T,D] fp32, split in-kernel); layers 2/3: x = prev h (hi+lo, [T,B,D])
    gru_scan<true,  2><<<4, 512, 0, stream>>>(X, nullptr, nullptr, Wr, Wk, bi, br, Ahi, Alo);
    gru_scan<false, 1><<<4, 512, 0, stream>>>(nullptr, Ahi, Alo,   Wr, Wk, bi, br, Bhi, Blo);
    gru_scan<false, 1><<<4, 512, 0, stream>>>(nullptr, Bhi, Blo,   Wr, Wk, bi, br, Ahi, Alo);
    out_proj<<<512, 512, 0, stream>>>(Ahi, Alo, Wo, bo, out);
}

// Round 3
// 12448.228 us; speedup vs baseline: 1.2262x; 1.2262x over previous
//
#include <hip/hip_runtime.h>
#include <stdint.h>

// Embedder_66932770341523: 3-layer shared-weight GRU (B=64,T=2048,H=128) + sigmoid proj.
// One kernel, 16 WGs = 4 batch-quarters x {L0, L1, L2, OutProj}, pipelined via
// L3-resident rings with agent-scope atomics (per-XCD L2s are not coherent).
#define TSEQ 2048
#define NB   64
#define HD   128
#define G3   384
#define W_RING 512
#define SLOT_U32 (16*128)                                   // 8 KB per step per quarter
#define RING_BYTES ((size_t)12 * W_RING * SLOT_U32 * 4)     // 3 ifaces x 4 quarters = 48 MB
#define FLAGS_OFF RING_BYTES

typedef __bf16 bf16_t;
typedef __bf16 bf16x8 __attribute__((ext_vector_type(8)));
typedef float  f32x4  __attribute__((ext_vector_type(4)));
typedef unsigned long long ull;

union B8 { uint4 u; bf16x8 v; unsigned a4[4]; };
union HU { bf16_t h; unsigned short u; };
static_assert(sizeof(B8) == 16, "B8 must be 16B");

__device__ __forceinline__ float fast_sigmoid(float x) {
    float e = __builtin_amdgcn_exp2f(-1.44269504f * x);
    return __builtin_amdgcn_rcpf(1.0f + e);
}
__device__ __forceinline__ float fast_tanh(float x) {
    x = fminf(9.0f, fmaxf(-9.0f, x));
    float e = __builtin_amdgcn_exp2f(2.88539008f * x);   // exp(2x)
    return 1.0f - 2.0f * __builtin_amdgcn_rcpf(1.0f + e);
}

#define MFMA16(A_, B_, C_) (C_) = __builtin_amdgcn_mfma_f32_16x16x32_bf16((A_), (B_), (C_), 0, 0, 0)

// --- agent-scope (cross-XCD) primitives: data bypasses local L2 via sc1 ---
__device__ __forceinline__ ull ld_agent_u64(const ull* p) {
    return __hip_atomic_load(p, __ATOMIC_RELAXED, __HIP_MEMORY_SCOPE_AGENT);
}
__device__ __forceinline__ void st_agent_u32(unsigned* p, unsigned v) {
    __hip_atomic_store(p, v, __ATOMIC_RELAXED, __HIP_MEMORY_SCOPE_AGENT);
}
__device__ __forceinline__ unsigned ld_flag_acq(const unsigned* p) {
    return __hip_atomic_load(p, __ATOMIC_ACQUIRE, __HIP_MEMORY_SCOPE_AGENT);
}
__device__ __forceinline__ void st_flag_rel(unsigned* p, unsigned v) {
    __hip_atomic_store(p, v, __ATOMIC_RELEASE, __HIP_MEMORY_SCOPE_AGENT);
}
// Bounded spin: never hang — on timeout mark dead and proceed (visible as absmax fail).
__device__ __forceinline__ unsigned spin_until(const unsigned* f, unsigned need,
                                               unsigned cur, bool& dead) {
    if (cur >= need) return cur;
    if (dead) return need;
    int g = 0;
    do {
        unsigned s = ld_flag_acq(f);
        if (s >= need) return s;
        __builtin_amdgcn_s_sleep(2);
    } while (++g < (1 << 15));
    dead = true;
    return need;
}

// MFMA 16x16x32 bf16 fragment maps (HW-verified, guide m89/m91/m120):
//   A: lane l, elem j -> A[l&15][(l>>4)*8 + j]
//   B: lane l, elem j -> B[(l>>4)*8 + j][l&15]
//   C/D: lane l, reg i -> C[(l>>4)*4 + i][l&15]

// One pipelined GRU timestep (PV = t&1 literal so indices fold).
// Order: publish flag -> deferred ring stores (t-1) -> issue input loads (t) ->
// ldsh A-frags -> gh MFMAs (hides load latency) -> unpack x -> gx MFMAs ->
// elementwise -> ldsh writes -> spin for t+1 -> barrier.
#define GRU_STEP(TT, PV)                                                              \
  {                                                                                   \
    if (tid == 0 && (TT) > 0) st_flag_rel(prod_out, (unsigned)((TT) - 1));            \
    if ((TT) > 0) {                                                                   \
      if ((int)((TT) - 1) - (int)cons_seen > W_RING - 80)                             \
        cons_seen = spin_until(cons_out, (unsigned)((TT) - 1) - (W_RING - 80),        \
                               cons_seen, dead);                                      \
      const int sb = (((TT) - 1) & (W_RING - 1)) * SLOT_U32;                          \
      _Pragma("unroll") for (int i = 0; i < 4; ++i)                                   \
        st_agent_u32(rout + sb + (4 * quad + i) * HD + cc, pend[i]);                  \
    }                                                                                 \
    ull raw[4][4];                                                                    \
    f32x4 xr0[4], xr1[4];                                                             \
    if (IN_RING) {                                                                    \
      const ull* ps = (const ull*)(rin + ((TT) & (W_RING - 1)) * SLOT_U32) + lane64;  \
      _Pragma("unroll") for (int q = 0; q < 4; ++q)                                   \
        _Pragma("unroll") for (int k = 0; k < 4; ++k)                                 \
          raw[q][k] = ld_agent_u64(ps + 16 * q + k);                                  \
    } else {                                                                          \
      const float* px = px0 + (TT) * HD;                                              \
      _Pragma("unroll") for (int q = 0; q < 4; ++q) {                                 \
        xr0[q] = *(const f32x4*)(px + 32 * q + 8 * quad);                             \
        xr1[q] = *(const f32x4*)(px + 32 * q + 8 * quad + 4);                         \
      }                                                                               \
    }                                                                                 \
    B8 ah[2][4];                                                                      \
    _Pragma("unroll") for (int hl = 0; hl < 2; ++hl)                                  \
      _Pragma("unroll") for (int q = 0; q < 4; ++q)                                   \
        ah[hl][q].u = ldsh[(PV) ^ 1][hl][q][lane];                                    \
    f32x4 accZ  = {bZ, bZ, bZ, bZ};                                                   \
    f32x4 accR  = {bR, bR, bR, bR};                                                   \
    f32x4 accXC = {bXC, bXC, bXC, bXC};                                               \
    f32x4 accHC = {bHC, bHC, bHC, bHC};                                               \
    _Pragma("unroll") for (int q = 0; q < 4; ++q) {  /* gh half first (hides x load) */\
      MFMA16(ah[0][q].v, Br[0][q], accZ);                                             \
      MFMA16(ah[0][q].v, Br[1][q], accR);                                             \
      MFMA16(ah[0][q].v, Br[2][q], accHC);                                            \
      MFMA16(ah[1][q].v, Br[0][q], accZ);                                             \
      MFMA16(ah[1][q].v, Br[1][q], accR);                                             \
      MFMA16(ah[1][q].v, Br[2][q], accHC);                                            \
    }                                                                                 \
    B8 xhi[4], xlo[4];                                                                \
    if (IN_RING) {                                                                    \
      _Pragma("unroll") for (int q = 0; q < 4; ++q)                                   \
        _Pragma("unroll") for (int k = 0; k < 4; ++k) {                               \
          const unsigned a = (unsigned)raw[q][k];                                     \
          const unsigned c = (unsigned)(raw[q][k] >> 32);                             \
          xhi[q].a4[k] = (a >> 16) | (c & 0xFFFF0000u);                               \
          xlo[q].a4[k] = (a & 0xFFFFu) | (c << 16);                                   \
        }                                                                             \
    } else {                                                                          \
      _Pragma("unroll") for (int q = 0; q < 4; ++q)                                   \
        _Pragma("unroll") for (int j = 0; j < 8; ++j) {                               \
          const float f = (j < 4) ? xr0[q][j] : xr1[q][j - 4];                        \
          const bf16_t hh = (bf16_t)f;                                                \
          xhi[q].v[j] = hh;                                                           \
          xlo[q].v[j] = (bf16_t)(f - (float)hh);                                      \
        }                                                                             \
    }                                                                                 \
    _Pragma("unroll") for (int q = 0; q < 4; ++q) {                                   \
      MFMA16(xhi[q].v, Bi_[0][q], accZ);                                              \
      MFMA16(xhi[q].v, Bi_[1][q], accR);                                              \
      MFMA16(xhi[q].v, Bi_[2][q], accXC);                                             \
      MFMA16(xlo[q].v, Bi_[0][q], accZ);                                              \
      MFMA16(xlo[q].v, Bi_[1][q], accR);                                              \
      MFMA16(xlo[q].v, Bi_[2][q], accXC);                                             \
    }                                                                                 \
    _Pragma("unroll") for (int i = 0; i < 4; ++i) {                                   \
      const float zg = fast_sigmoid(accZ[i]);                                         \
      const float rg = fast_sigmoid(accR[i]);                                         \
      const float cd = fast_tanh(accXC[i] + rg * accHC[i]);                           \
      const float hn = cd + zg * (hprev[i] - cd);                                     \
      hprev[i] = hn;                                                                  \
      HU hh; hh.h = (bf16_t)hn;                                                       \
      HU hl_; hl_.h = (bf16_t)(hn - (float)hh.h);                                     \
      pend[i] = ((unsigned)hh.u << 16) | (unsigned)hl_.u;                             \
      const int mrow = 4 * quad + i;                                                  \
      ((bf16_t*)&ldsh[(PV)][0][qq][lamb + mrow])[jj] = hh.h;                          \
      ((bf16_t*)&ldsh[(PV)][1][qq][lamb + mrow])[jj] = hl_.h;                         \
    }                                                                                 \
    if (IN_RING && (TT) < TSEQ - 1)                                                   \
      seen = spin_until(prod_in, (unsigned)((TT) + 2), seen, dead);                   \
    if (IN_RING && tid == 0 && (((TT) & 15) == 15))                                   \
      st_agent_u32(cons_in, (unsigned)(TT));                                          \
    __syncthreads();                                                                  \
  }

// One GRU pipeline stage. 512 threads = 8 waves; wave w owns h-cols [16w,16w+16).
// h state fp32 in registers; recurrent A-operand = bf16 hi+lo via LDS (as R1).
template <bool IN_RING>
__device__ __forceinline__ void gru_stage(
    uint4 (*ldsh)[2][4][64],
    const float* __restrict__ X,          // stage0 input [B,T,D] fp32 (else null)
    const unsigned* __restrict__ rin,     // ring in  (u32 = hi<<16|lo), null for stage0
    unsigned* __restrict__ rout,          // ring out
    unsigned* prod_in, unsigned* cons_in, // upstream flags (poll / publish)
    unsigned* prod_out, unsigned* cons_out, // our flags (publish / poll)
    const float* __restrict__ Wrec, const float* __restrict__ Win,
    const float* __restrict__ bin, const float* __restrict__ brec, int b)
{
    const int tid  = threadIdx.x;
    const int w    = tid >> 6;
    const int lane = tid & 63;
    const int l15  = lane & 15;
    const int quad = lane >> 4;

    // B-fragments resident for the whole scan (shared across all 3 layers anyway).
    bf16x8 Br[3][4];
    bf16x8 Bi_[3][4];
#pragma unroll
    for (int g = 0; g < 3; ++g)
#pragma unroll
        for (int q = 0; q < 4; ++q) {
            const int col = 128 * g + 16 * w + l15;
#pragma unroll
            for (int j = 0; j < 8; ++j) {
                const int row = 32 * q + 8 * quad + j;
                Br[g][q][j]  = (bf16_t)Wrec[row * G3 + col];
                Bi_[g][q][j] = (bf16_t)Win[row * G3 + col];
            }
        }

    const int cc    = 16 * w + l15;
    const float bZ  = bin[cc] + brec[cc];
    const float bR  = bin[128 + cc] + brec[128 + cc];
    const float bXC = bin[256 + cc];
    const float bHC = brec[256 + cc];

    const float* px0 = IN_RING ? nullptr : (X + (size_t)(16 * b + l15) * TSEQ * HD);
    const int lane64 = l15 * 64 + 4 * quad;   // u64 index of this lane's frag base

    {   // zero parity-1 h buffers (read at t=0)
        uint4 z4; z4.x = z4.y = z4.z = z4.w = 0u;
        ldsh[1][tid >> 8][(tid >> 6) & 3][tid & 63] = z4;
    }
    // LDS write mapping: A[m][k=cc] -> frag q=cc>>5, lane=m+16*((cc>>3)&3), elem cc&7
    const int qq   = cc >> 5;
    const int lamb = 16 * ((cc >> 3) & 3);
    const int jj   = cc & 7;

    float hprev[4] = {0.f, 0.f, 0.f, 0.f};
    unsigned pend[4] = {0u, 0u, 0u, 0u};
    unsigned seen = 0, cons_seen = 0;
    bool dead = false;

    if (IN_RING) seen = spin_until(prod_in, 1u, seen, dead);  // gate slot 0
    __syncthreads();

    for (int t = 0; t < TSEQ; t += 2) {
        GRU_STEP(t, 0)
        GRU_STEP(t + 1, 1)
    }
    {   // flush final slot, then publish full completion
        const int sb = ((TSEQ - 1) & (W_RING - 1)) * SLOT_U32;
#pragma unroll
        for (int i = 0; i < 4; ++i)
            st_agent_u32(rout + sb + (4 * quad + i) * HD + cc, pend[i]);
    }
    __syncthreads();
    if (tid == 0) st_flag_rel(prod_out, (unsigned)TSEQ);
}

// Stage 3: out(t) = sigmoid(h3(t) @ W_out + b_out), consuming ring2. No LDS needed.
__device__ __forceinline__ void outproj_stage(
    const unsigned* __restrict__ rin, unsigned* prod_in, unsigned* cons_in,
    const float* __restrict__ Wout, const float* __restrict__ bout,
    float* __restrict__ out, int b)
{
    const int tid  = threadIdx.x;
    const int w    = tid >> 6;
    const int lane = tid & 63;
    const int l15  = lane & 15;
    const int quad = lane >> 4;

    bf16x8 Bw[4];
#pragma unroll
    for (int q = 0; q < 4; ++q)
#pragma unroll
        for (int j = 0; j < 8; ++j)
            Bw[q][j] = (bf16_t)Wout[(32 * q + 8 * quad + j) * HD + 16 * w + l15];
    const float bb = bout[16 * w + l15];
    const int lane64 = l15 * 64 + 4 * quad;

    ull raw[2][4][4];
    unsigned seen = 0;
    bool dead = false;
    seen = spin_until(prod_in, 1u, seen, dead);
    {
        const ull* ps = (const ull*)(rin + 0) + lane64;
#pragma unroll
        for (int q = 0; q < 4; ++q)
#pragma unroll
            for (int k = 0; k < 4; ++k) raw[0][q][k] = ld_agent_u64(ps + 16 * q + k);
    }
    for (int t = 0; t < TSEQ; ++t) {
        if (t < TSEQ - 1) {   // prefetch next slot
            seen = spin_until(prod_in, (unsigned)(t + 2), seen, dead);
            const ull* ps = (const ull*)(rin + ((t + 1) & (W_RING - 1)) * SLOT_U32) + lane64;
#pragma unroll
            for (int q = 0; q < 4; ++q)
#pragma unroll
                for (int k = 0; k < 4; ++k)
                    raw[(t + 1) & 1][q][k] = ld_agent_u64(ps + 16 * q + k);
        }
        B8 ahhi[4], ahlo[4];
#pragma unroll
        for (int q = 0; q < 4; ++q)
#pragma unroll
            for (int k = 0; k < 4; ++k) {
                const ull d = raw[t & 1][q][k];
                const unsigned a = (unsigned)d;
                const unsigned c = (unsigned)(d >> 32);
                ahhi[q].a4[k] = (a >> 16) | (c & 0xFFFF0000u);
                ahlo[q].a4[k] = (a & 0xFFFFu) | (c << 16);
            }
        f32x4 acc = {bb, bb, bb, bb};
#pragma unroll
        for (int q = 0; q < 4; ++q) {
            MFMA16(ahhi[q].v, Bw[q], acc);
            MFMA16(ahlo[q].v, Bw[q], acc);
        }
#pragma unroll
        for (int i = 0; i < 4; ++i) {
            const float s = fast_sigmoid(acc[i]);
            out[(size_t)((16 * b + 4 * quad + i) * TSEQ + t) * HD + 16 * w + l15] = s;
        }
        if ((t & 63) == 63) {   // bound wave skew; publish consumption progress
            __syncthreads();
            if (tid == 0) st_agent_u32(cons_in, (unsigned)t);
        }
    }
}

__global__ __launch_bounds__(512, 2) void fused_gru(
    const float* __restrict__ X,
    const float* __restrict__ Wk, const float* __restrict__ Wr,
    const float* __restrict__ bi, const float* __restrict__ br,
    const float* __restrict__ Wo, const float* __restrict__ bo,
    float* __restrict__ out, unsigned char* __restrict__ ws)
{
    __shared__ uint4 ldsh[2][2][4][64];
    const int stage = blockIdx.x >> 2;
    const int b     = blockIdx.x & 3;
    unsigned* F = (unsigned*)(ws + FLAGS_OFF);
    unsigned* ring0 = (unsigned*)ws + (size_t)(0 * 4 + b) * W_RING * SLOT_U32;
    unsigned* ring1 = (unsigned*)ws + (size_t)(1 * 4 + b) * W_RING * SLOT_U32;
    unsigned* ring2 = (unsigned*)ws + (size_t)(2 * 4 + b) * W_RING * SLOT_U32;
    unsigned* p0 = F + (0 * 4 + b) * 64, *c0 = p0 + 32;   // ring0 prod/cons flags
    unsigned* p1 = F + (1 * 4 + b) * 64, *c1 = p1 + 32;
    unsigned* p2 = F + (2 * 4 + b) * 64, *c2 = p2 + 32;

    if (stage == 0)
        gru_stage<false>(ldsh, X, nullptr, ring0, nullptr, nullptr, p0, c0, Wr, Wk, bi, br, b);
    else if (stage == 1)
        gru_stage<true>(ldsh, nullptr, ring0, ring1, p0, c0, p1, c1, Wr, Wk, bi, br, b);
    else if (stage == 2)
        gru_stage<true>(ldsh, nullptr, ring1, ring2, p1, c1, p2, c2, Wr, Wk, bi, br, b);
    else
        outproj_stage(ring2, p2, c2, Wo, bo, out, b);
}

extern "C" void kernel_launch(void* const* d_in, const int* in_sizes, int n_in,
                              void* d_out, int out_size, void* d_ws, size_t ws_size,
                              hipStream_t stream) {
    const float* X  = (const float*)d_in[0];
    const float* Wk = (const float*)d_in[1];
    const float* Wr = (const float*)d_in[2];
    const float* bi = (const float*)d_in[3];
    const float* br = (const float*)d_in[4];
    const float* Wo = (const float*)d_in[5];
    const float* bo = (const float*)d_in[6];
    float* out = (float*)d_out;

    if (ws_size < RING_BYTES + 4096) return;  // distinctive fail instead of OOB scribble
    // Flags must start at 0 (ws is poisoned 0xAA before every launch).
    hipMemsetAsync((char*)d_ws + FLAGS_OFF, 0, 4096, stream);
    fused_gru<<<16, 512, 0, stream>>>(X, Wk, Wr, bi, br, Wo, bo, out,
                                      (unsigned char*)d_ws);
}

// Round 4
// 12360.078 us; speedup vs baseline: 1.2349x; 1.0071x over previous
//
#include <hip/hip_runtime.h>
#include <stdint.h>

// Embedder_66932770341523: 3-layer shared-weight GRU (B=64,T=2048,H=128) + sigmoid proj.
// One kernel, 16 WGs = 4 batch-quarters x {L0, L1, L2, OutProj}, pipelined via
// L3-resident rings with agent-scope atomics (per-XCD L2s are not coherent).
#define TSEQ 2048
#define NB   64
#define HD   128
#define G3   384
#define W_RING 128
#define SLOT_U32 (16*128)                                   // 8 KB per step per quarter
#define RING_BYTES ((size_t)12 * W_RING * SLOT_U32 * 4)     // 3 ifaces x 4 quarters = 12 MB
#define FLAGS_OFF RING_BYTES

typedef __bf16 bf16_t;
typedef __bf16 bf16x8 __attribute__((ext_vector_type(8)));
typedef float  f32x4  __attribute__((ext_vector_type(4)));
typedef unsigned long long ull;

union B8 { uint4 u; bf16x8 v; unsigned a4[4]; };
union HU { bf16_t h; unsigned short u; };
static_assert(sizeof(B8) == 16, "B8 must be 16B");

__device__ __forceinline__ float fast_sigmoid(float x) {
    float e = __builtin_amdgcn_exp2f(-1.44269504f * x);
    return __builtin_amdgcn_rcpf(1.0f + e);
}
__device__ __forceinline__ float fast_tanh(float x) {
    x = fminf(9.0f, fmaxf(-9.0f, x));
    float e = __builtin_amdgcn_exp2f(2.88539008f * x);   // exp(2x)
    return 1.0f - 2.0f * __builtin_amdgcn_rcpf(1.0f + e);
}

#define MFMA16(A_, B_, C_) (C_) = __builtin_amdgcn_mfma_f32_16x16x32_bf16((A_), (B_), (C_), 0, 0, 0)

// Barriers: LDS-only visibility (lets global loads/stores stay in flight across
// the barrier — __syncthreads would drain vmcnt(0) and kill the prefetch), and
// a full-drain variant used every 16th step to make flag publication airtight.
__device__ __forceinline__ void fast_barrier() {
    asm volatile("s_waitcnt lgkmcnt(0)\n\ts_barrier" ::: "memory");
}
__device__ __forceinline__ void full_barrier() {
    asm volatile("s_waitcnt vmcnt(0) lgkmcnt(0)\n\ts_barrier" ::: "memory");
}

// --- agent-scope (cross-XCD, L3-coherent) primitives ---
__device__ __forceinline__ ull ld_agent_u64(const ull* p) {
    return __hip_atomic_load(p, __ATOMIC_RELAXED, __HIP_MEMORY_SCOPE_AGENT);
}
__device__ __forceinline__ void st_agent_u32(unsigned* p, unsigned v) {
    __hip_atomic_store(p, v, __ATOMIC_RELAXED, __HIP_MEMORY_SCOPE_AGENT);
}
__device__ __forceinline__ unsigned ld_flag_rlx(const unsigned* p) {
    return __hip_atomic_load(p, __ATOMIC_RELAXED, __HIP_MEMORY_SCOPE_AGENT);
}
__device__ __forceinline__ void st_flag_rel(unsigned* p, unsigned v) {
    __hip_atomic_store(p, v, __ATOMIC_RELEASE, __HIP_MEMORY_SCOPE_AGENT);
}
// Relaxed poll. Safety: producer publishes only after a full vmcnt(0) barrier
// (all waves' slot stores acked at L3) + release store; consumer's data loads are
// agent-scope (straight to L3) and control-dependent on the observed flag value,
// so on this in-order machine flag-observed => slot data readable. Bounded spin:
// on timeout mark dead and proceed (absmax check catches it; never hangs).
__device__ __forceinline__ unsigned spin_until(const unsigned* f, unsigned need,
                                               unsigned cur, bool& dead) {
    if (cur >= need) return cur;
    if (dead) return need;
    int g = 0;
    do {
        unsigned s = ld_flag_rlx(f);
        if (s >= need) { asm volatile("" ::: "memory"); return s; }
        __builtin_amdgcn_s_sleep(2);
    } while (++g < (1 << 15));
    dead = true;
    return need;
}

// MFMA 16x16x32 bf16 fragment maps (HW-verified, guide m89/m91/m120):
//   A: lane l, elem j -> A[l&15][(l>>4)*8 + j]
//   B: lane l, elem j -> B[(l>>4)*8 + j][l&15]
//   C/D: lane l, reg i -> C[(l>>4)*4 + i][l&15]

#define LOADRING(DST, TT2)                                                            \
    { const ull* ps = (const ull*)(rin + ((TT2) & (W_RING - 1)) * SLOT_U32) + lane64; \
      _Pragma("unroll") for (int q = 0; q < 4; ++q)                                   \
        _Pragma("unroll") for (int k = 0; k < 4; ++k)                                 \
          raw[DST][q][k] = ld_agent_u64(ps + 16 * q + k); }

#define LOADF32(DST, TT2)                                                             \
    { const float* px = px0 + (TT2) * HD;                                             \
      _Pragma("unroll") for (int q = 0; q < 4; ++q) {                                 \
        xr0[DST][q] = *(const f32x4*)(px + 32 * q + 8 * quad);                        \
        xr1[DST][q] = *(const f32x4*)(px + 32 * q + 8 * quad + 4); } }

// One pipelined GRU timestep (PV = t&1 literal so indices fold).
// Order: ds_read A-frags -> periodic flag publish -> deferred ring stores (t-1)
// -> unpack prefetched x -> gx MFMAs (covers LDS latency) -> gh MFMAs ->
// elementwise -> LDS writes -> flag check + prefetch input(t+1) -> barrier
// (prefetch stays in flight across it).
#define GRU_STEP(TT, PV)                                                              \
  {                                                                                   \
    B8 ah[2][4];                                                                      \
    _Pragma("unroll") for (int hl = 0; hl < 2; ++hl)                                  \
      _Pragma("unroll") for (int q = 0; q < 4; ++q)                                   \
        ah[hl][q].u = ldsh[(PV) ^ 1][hl][q][lane];                                    \
    if ((((TT) & 15) == 0) && (TT) > 0 && tid == 0)                                   \
      st_flag_rel(prod_out, (unsigned)(TT) - 1u);  /* covers slots <= TT-2 */         \
    if ((TT) > 0) {                                                                   \
      if ((int)((TT) - 1) - (int)cons_seen > W_RING - 80)                             \
        cons_seen = spin_until(cons_out, (unsigned)((TT) - 1) - (W_RING - 80),        \
                               cons_seen, dead);                                      \
      const int sb = (((TT) - 1) & (W_RING - 1)) * SLOT_U32;                          \
      _Pragma("unroll") for (int i = 0; i < 4; ++i)                                   \
        st_agent_u32(rout + sb + (4 * quad + i) * HD + cc, pend[i]);                  \
    }                                                                                 \
    B8 xhi[4], xlo[4];                                                                \
    if (IN_RING) {                                                                    \
      _Pragma("unroll") for (int q = 0; q < 4; ++q)                                   \
        _Pragma("unroll") for (int k = 0; k < 4; ++k) {                               \
          const unsigned a = (unsigned)raw[PV][q][k];                                 \
          const unsigned c = (unsigned)(raw[PV][q][k] >> 32);                         \
          xhi[q].a4[k] = (a >> 16) | (c & 0xFFFF0000u);                               \
          xlo[q].a4[k] = (a & 0xFFFFu) | (c << 16);                                   \
        }                                                                             \
    } else {                                                                          \
      _Pragma("unroll") for (int q = 0; q < 4; ++q)                                   \
        _Pragma("unroll") for (int j = 0; j < 8; ++j) {                               \
          const float f = (j < 4) ? xr0[PV][q][j] : xr1[PV][q][j - 4];                \
          const bf16_t hh = (bf16_t)f;                                                \
          xhi[q].v[j] = hh;                                                           \
          xlo[q].v[j] = (bf16_t)(f - (float)hh);                                      \
        }                                                                             \
    }                                                                                 \
    f32x4 accZ  = {bZ, bZ, bZ, bZ};                                                   \
    f32x4 accR  = {bR, bR, bR, bR};                                                   \
    f32x4 accXC = {bXC, bXC, bXC, bXC};                                               \
    f32x4 accHC = {bHC, bHC, bHC, bHC};                                               \
    _Pragma("unroll") for (int q = 0; q < 4; ++q) {  /* gx first: covers ds_read */   \
      MFMA16(xhi[q].v, Bi_[0][q], accZ);                                              \
      MFMA16(xhi[q].v, Bi_[1][q], accR);                                              \
      MFMA16(xhi[q].v, Bi_[2][q], accXC);                                             \
      MFMA16(xlo[q].v, Bi_[0][q], accZ);                                              \
      MFMA16(xlo[q].v, Bi_[1][q], accR);                                              \
      MFMA16(xlo[q].v, Bi_[2][q], accXC);                                             \
    }                                                                                 \
    _Pragma("unroll") for (int q = 0; q < 4; ++q) {                                   \
      MFMA16(ah[0][q].v, Br[0][q], accZ);                                             \
      MFMA16(ah[0][q].v, Br[1][q], accR);                                             \
      MFMA16(ah[0][q].v, Br[2][q], accHC);                                            \
      MFMA16(ah[1][q].v, Br[0][q], accZ);                                             \
      MFMA16(ah[1][q].v, Br[1][q], accR);                                             \
      MFMA16(ah[1][q].v, Br[2][q], accHC);                                            \
    }                                                                                 \
    _Pragma("unroll") for (int i = 0; i < 4; ++i) {                                   \
      const float zg = fast_sigmoid(accZ[i]);                                         \
      const float rg = fast_sigmoid(accR[i]);                                         \
      const float cd = fast_tanh(accXC[i] + rg * accHC[i]);                           \
      const float hn = cd + zg * (hprev[i] - cd);                                     \
      hprev[i] = hn;                                                                  \
      HU hh; hh.h = (bf16_t)hn;                                                       \
      HU hl_; hl_.h = (bf16_t)(hn - (float)hh.h);                                     \
      pend[i] = ((unsigned)hh.u << 16) | (unsigned)hl_.u;                             \
      const int mrow = 4 * quad + i;                                                  \
      ((bf16_t*)&ldsh[(PV)][0][qq][lamb + mrow])[jj] = hh.h;                          \
      ((bf16_t*)&ldsh[(PV)][1][qq][lamb + mrow])[jj] = hl_.h;                         \
    }                                                                                 \
    if ((TT) < TSEQ - 1) {  /* prefetch input for t+1; flies across the barrier */    \
      if (IN_RING) {                                                                  \
        seen = spin_until(prod_in, (unsigned)(TT) + 2u, seen, dead);                  \
        LOADRING((PV) ^ 1, (TT) + 1);                                                 \
      } else {                                                                        \
        LOADF32((PV) ^ 1, (TT) + 1);                                                  \
      }                                                                               \
    }                                                                                 \
    if (IN_RING && tid == 0 && (((TT) & 7) == 7))                                     \
      st_agent_u32(cons_in, (unsigned)(TT));                                          \
    if ((((TT) + 1) & 15) == 0) full_barrier(); else fast_barrier();                  \
  }

// One GRU pipeline stage. 512 threads = 8 waves; wave w owns h-cols [16w,16w+16).
// h state fp32 in registers; recurrent A-operand = bf16 hi+lo via LDS.
template <bool IN_RING>
__device__ __forceinline__ void gru_stage(
    uint4 (*ldsh)[2][4][64],
    const float* __restrict__ X,            // stage0 input [B,T,D] fp32 (else null)
    const unsigned* __restrict__ rin,       // ring in (u32 = hi<<16|lo), null for stage0
    unsigned* __restrict__ rout,            // ring out
    unsigned* prod_in, unsigned* cons_in,   // upstream flags (poll / publish)
    unsigned* prod_out, unsigned* cons_out, // our flags (publish / poll)
    const float* __restrict__ Wrec, const float* __restrict__ Win,
    const float* __restrict__ bin, const float* __restrict__ brec, int b)
{
    const int tid  = threadIdx.x;
    const int w    = tid >> 6;
    const int lane = tid & 63;
    const int l15  = lane & 15;
    const int quad = lane >> 4;

    // B-fragments resident for the whole scan (fp32 weights -> bf16 once).
    bf16x8 Br[3][4];
    bf16x8 Bi_[3][4];
#pragma unroll
    for (int g = 0; g < 3; ++g)
#pragma unroll
        for (int q = 0; q < 4; ++q) {
            const int col = 128 * g + 16 * w + l15;
#pragma unroll
            for (int j = 0; j < 8; ++j) {
                const int row = 32 * q + 8 * quad + j;
                Br[g][q][j]  = (bf16_t)Wrec[row * G3 + col];
                Bi_[g][q][j] = (bf16_t)Win[row * G3 + col];
            }
        }

    const int cc    = 16 * w + l15;
    const float bZ  = bin[cc] + brec[cc];
    const float bR  = bin[128 + cc] + brec[128 + cc];
    const float bXC = bin[256 + cc];
    const float bHC = brec[256 + cc];

    const float* px0 = IN_RING ? nullptr : (X + (size_t)(16 * b + l15) * TSEQ * HD);
    const int lane64 = l15 * 64 + 4 * quad;   // u64 index of this lane's frag base

    {   // zero parity-1 h buffers (read at t=0)
        uint4 z4; z4.x = z4.y = z4.z = z4.w = 0u;
        ldsh[1][tid >> 8][(tid >> 6) & 3][tid & 63] = z4;
    }
    // LDS write mapping: A[m][k=cc] -> frag q=cc>>5, lane=m+16*((cc>>3)&3), elem cc&7
    const int qq   = cc >> 5;
    const int lamb = 16 * ((cc >> 3) & 3);
    const int jj   = cc & 7;

    float hprev[4] = {0.f, 0.f, 0.f, 0.f};
    unsigned pend[4] = {0u, 0u, 0u, 0u};
    unsigned seen = 0, cons_seen = 0;
    bool dead = false;

    ull   raw[2][4][4];   // ring-input double buffer (IN_RING)
    f32x4 xr0[2][4], xr1[2][4];  // fp32-input double buffer (stage0)

    if (IN_RING) {
        seen = spin_until(prod_in, 1u, seen, dead);  // slot 0 valid iff flag >= 1
        LOADRING(0, 0);
    } else {
        LOADF32(0, 0);
    }
    __syncthreads();

    for (int t = 0; t < TSEQ; t += 2) {
        GRU_STEP(t, 0)
        GRU_STEP(t + 1, 1)
    }
    {   // flush final slot; full drain (all waves) then airtight release publish
        const int sb = ((TSEQ - 1) & (W_RING - 1)) * SLOT_U32;
#pragma unroll
        for (int i = 0; i < 4; ++i)
            st_agent_u32(rout + sb + (4 * quad + i) * HD + cc, pend[i]);
    }
    __syncthreads();   // includes vmcnt(0) drain for all waves
    if (tid == 0) {
        st_flag_rel(prod_out, (unsigned)TSEQ + 2u);
        if (IN_RING) st_agent_u32(cons_in, (unsigned)TSEQ);
    }
}

// Stage 3: out(t) = sigmoid(h3(t) @ W_out + b_out), consuming ring2.
__device__ __forceinline__ void outproj_stage(
    const unsigned* __restrict__ rin, unsigned* prod_in, unsigned* cons_in,
    const float* __restrict__ Wout, const float* __restrict__ bout,
    float* __restrict__ out, int b)
{
    const int tid  = threadIdx.x;
    const int w    = tid >> 6;
    const int lane = tid & 63;
    const int l15  = lane & 15;
    const int quad = lane >> 4;

    bf16x8 Bw[4];
#pragma unroll
    for (int q = 0; q < 4; ++q)
#pragma unroll
        for (int j = 0; j < 8; ++j)
            Bw[q][j] = (bf16_t)Wout[(32 * q + 8 * quad + j) * HD + 16 * w + l15];
    const float bb = bout[16 * w + l15];
    const int lane64 = l15 * 64 + 4 * quad;

    ull raw[2][4][4];
    unsigned seen = 0;
    bool dead = false;
    seen = spin_until(prod_in, 1u, seen, dead);
    {
        const ull* ps = (const ull*)(rin + 0) + lane64;
#pragma unroll
        for (int q = 0; q < 4; ++q)
#pragma unroll
            for (int k = 0; k < 4; ++k) raw[0][q][k] = ld_agent_u64(ps + 16 * q + k);
    }
    for (int t = 0; t < TSEQ; ++t) {
        if (t < TSEQ - 1) {   // prefetch next slot (slot s valid iff flag >= s+1)
            seen = spin_until(prod_in, (unsigned)(t + 2), seen, dead);
            const ull* ps = (const ull*)(rin + ((t + 1) & (W_RING - 1)) * SLOT_U32) + lane64;
#pragma unroll
            for (int q = 0; q < 4; ++q)
#pragma unroll
                for (int k = 0; k < 4; ++k)
                    raw[(t + 1) & 1][q][k] = ld_agent_u64(ps + 16 * q + k);
        }
        B8 ahhi[4], ahlo[4];
#pragma unroll
        for (int q = 0; q < 4; ++q)
#pragma unroll
            for (int k = 0; k < 4; ++k) {
                const ull d = raw[t & 1][q][k];
                const unsigned a = (unsigned)d;
                const unsigned c = (unsigned)(d >> 32);
                ahhi[q].a4[k] = (a >> 16) | (c & 0xFFFF0000u);
                ahlo[q].a4[k] = (a & 0xFFFFu) | (c << 16);
            }
        f32x4 acc = {bb, bb, bb, bb};
#pragma unroll
        for (int q = 0; q < 4; ++q) {
            MFMA16(ahhi[q].v, Bw[q], acc);
            MFMA16(ahlo[q].v, Bw[q], acc);
        }
#pragma unroll
        for (int i = 0; i < 4; ++i) {
            const float s = fast_sigmoid(acc[i]);
            out[(size_t)((16 * b + 4 * quad + i) * TSEQ + t) * HD + 16 * w + l15] = s;
        }
        if (tid == 0 && ((t & 7) == 7)) st_agent_u32(cons_in, (unsigned)t);
    }
}

__global__ __launch_bounds__(512, 1) void fused_gru(
    const float* __restrict__ X,
    const float* __restrict__ Wk, const float* __restrict__ Wr,
    const float* __restrict__ bi, const float* __restrict__ br,
    const float* __restrict__ Wo, const float* __restrict__ bo,
    float* __restrict__ out, unsigned char* __restrict__ ws)
{
    __shared__ uint4 ldsh[2][2][4][64];
    const int stage = blockIdx.x >> 2;
    const int b     = blockIdx.x & 3;
    unsigned* F = (unsigned*)(ws + FLAGS_OFF);
    unsigned* ring0 = (unsigned*)ws + (size_t)(0 * 4 + b) * W_RING * SLOT_U32;
    unsigned* ring1 = (unsigned*)ws + (size_t)(1 * 4 + b) * W_RING * SLOT_U32;
    unsigned* ring2 = (unsigned*)ws + (size_t)(2 * 4 + b) * W_RING * SLOT_U32;
    unsigned* p0 = F + (0 * 4 + b) * 64, *c0 = p0 + 32;   // ring0 prod/cons flags
    unsigned* p1 = F + (1 * 4 + b) * 64, *c1 = p1 + 32;
    unsigned* p2 = F + (2 * 4 + b) * 64, *c2 = p2 + 32;

    if (stage == 0)
        gru_stage<false>(ldsh, X, nullptr, ring0, nullptr, nullptr, p0, c0, Wr, Wk, bi, br, b);
    else if (stage == 1)
        gru_stage<true>(ldsh, nullptr, ring0, ring1, p0, c0, p1, c1, Wr, Wk, bi, br, b);
    else if (stage == 2)
        gru_stage<true>(ldsh, nullptr, ring1, ring2, p1, c1, p2, c2, Wr, Wk, bi, br, b);
    else
        outproj_stage(ring2, p2, c2, Wo, bo, out, b);
}

extern "C" void kernel_launch(void* const* d_in, const int* in_sizes, int n_in,
                              void* d_out, int out_size, void* d_ws, size_t ws_size,
                              hipStream_t stream) {
    const float* X  = (const float*)d_in[0];
    const float* Wk = (const float*)d_in[1];
    const float* Wr = (const float*)d_in[2];
    const float* bi = (const float*)d_in[3];
    const float* br = (const float*)d_in[4];
    const float* Wo = (const float*)d_in[5];
    const float* bo = (const float*)d_in[6];
    float* out = (float*)d_out;

    if (ws_size < RING_BYTES + 4096) return;  // distinctive fail instead of OOB scribble
    // Flags must start at 0 (ws is poisoned 0xAA before every launch).
    hipMemsetAsync((char*)d_ws + FLAGS_OFF, 0, 4096, stream);
    fused_gru<<<16, 512, 0, stream>>>(X, Wk, Wr, bi, br, Wo, bo, out,
                                      (unsigned char*)d_ws);
}